// Round 13
// baseline (293.716 us; speedup 1.0000x reference)
//
#include <hip/hip_runtime.h>

// x: (16, 3, 1024, 1024) f32  ->  out: (16, 4, 512, 512) f32
// gray = 0.114*x[:,0] + 0.587*x[:,1] + 0.299*x[:,2]
// 2x2 Haar butterfly per 2x2 block; outputs 4 planes (cA,cH,cV,cD).
//
// Memory-bound: ideal traffic = 192 MiB in + 64 MiB out ~= 268 MB -> ~43 us
// at 6.3 TB/s. Zero reuse -> nontemporal loads/stores (nt flag) to skip
// L2/L3 allocation on the pure stream (R12 showed ~90us residual vs 43us
// roofline; hypothesis: cache fill+evict overhead on 835 MB streaming).

#define B_  16
#define H_  1024
#define W_  1024
#define OH_ 512
#define OW_ 512

typedef float f4 __attribute__((ext_vector_type(4)));

__global__ __launch_bounds__(256) void haar_gray_kernel(
    const float* __restrict__ x, float* __restrict__ out)
{
    // one thread = 4 output pixels (8 input cols x 2 input rows)
    // total threads = 16 * 512 * 128 = 1,048,576
    const int tid = blockIdx.x * blockDim.x + threadIdx.x;

    const int b   = tid >> 16;              // / (512*128)
    const int rem = tid & ((1 << 16) - 1);
    const int i   = rem >> 7;               // output row
    const int tj  = rem & 127;              // quad index within row
    const int j0  = tj << 2;                // output col (multiple of 4 -> 16B aligned)
    const int w0  = tj << 3;                // input col (multiple of 8 -> 32B aligned)
    const int h0  = i << 1;                 // input row (top of pair)

    const float* bp = x + (size_t)b * 3 * H_ * W_;

    const float wb = 0.114f, wg = 0.587f, wr = 0.299f;

    // 3 channels x {top,bottom} x 2 f4 = 12 x 16B coalesced nontemporal loads
    const f4* p0t = reinterpret_cast<const f4*>(bp + (size_t)(0 * H_ + h0    ) * W_ + w0);
    const f4* p0b = reinterpret_cast<const f4*>(bp + (size_t)(0 * H_ + h0 + 1) * W_ + w0);
    const f4* p1t = reinterpret_cast<const f4*>(bp + (size_t)(1 * H_ + h0    ) * W_ + w0);
    const f4* p1b = reinterpret_cast<const f4*>(bp + (size_t)(1 * H_ + h0 + 1) * W_ + w0);
    const f4* p2t = reinterpret_cast<const f4*>(bp + (size_t)(2 * H_ + h0    ) * W_ + w0);
    const f4* p2b = reinterpret_cast<const f4*>(bp + (size_t)(2 * H_ + h0 + 1) * W_ + w0);

    const f4 a0q0 = __builtin_nontemporal_load(p0t + 0);
    const f4 a0q1 = __builtin_nontemporal_load(p0t + 1);
    const f4 b0q0 = __builtin_nontemporal_load(p0b + 0);
    const f4 b0q1 = __builtin_nontemporal_load(p0b + 1);
    const f4 a1q0 = __builtin_nontemporal_load(p1t + 0);
    const f4 a1q1 = __builtin_nontemporal_load(p1t + 1);
    const f4 b1q0 = __builtin_nontemporal_load(p1b + 0);
    const f4 b1q1 = __builtin_nontemporal_load(p1b + 1);
    const f4 a2q0 = __builtin_nontemporal_load(p2t + 0);
    const f4 a2q1 = __builtin_nontemporal_load(p2t + 1);
    const f4 b2q0 = __builtin_nontemporal_load(p2b + 0);
    const f4 b2q1 = __builtin_nontemporal_load(p2b + 1);

    // gray, top row (8 px) and bottom row (8 px)
    const float gt0 = fmaf(wb, a0q0.x, fmaf(wg, a1q0.x, wr * a2q0.x));
    const float gt1 = fmaf(wb, a0q0.y, fmaf(wg, a1q0.y, wr * a2q0.y));
    const float gt2 = fmaf(wb, a0q0.z, fmaf(wg, a1q0.z, wr * a2q0.z));
    const float gt3 = fmaf(wb, a0q0.w, fmaf(wg, a1q0.w, wr * a2q0.w));
    const float gt4 = fmaf(wb, a0q1.x, fmaf(wg, a1q1.x, wr * a2q1.x));
    const float gt5 = fmaf(wb, a0q1.y, fmaf(wg, a1q1.y, wr * a2q1.y));
    const float gt6 = fmaf(wb, a0q1.z, fmaf(wg, a1q1.z, wr * a2q1.z));
    const float gt7 = fmaf(wb, a0q1.w, fmaf(wg, a1q1.w, wr * a2q1.w));
    const float gb0 = fmaf(wb, b0q0.x, fmaf(wg, b1q0.x, wr * b2q0.x));
    const float gb1 = fmaf(wb, b0q0.y, fmaf(wg, b1q0.y, wr * b2q0.y));
    const float gb2 = fmaf(wb, b0q0.z, fmaf(wg, b1q0.z, wr * b2q0.z));
    const float gb3 = fmaf(wb, b0q0.w, fmaf(wg, b1q0.w, wr * b2q0.w));
    const float gb4 = fmaf(wb, b0q1.x, fmaf(wg, b1q1.x, wr * b2q1.x));
    const float gb5 = fmaf(wb, b0q1.y, fmaf(wg, b1q1.y, wr * b2q1.y));
    const float gb6 = fmaf(wb, b0q1.z, fmaf(wg, b1q1.z, wr * b2q1.z));
    const float gb7 = fmaf(wb, b0q1.w, fmaf(wg, b1q1.w, wr * b2q1.w));

    // Haar butterfly, four 2x2 blocks -> one f4 per output plane
    f4 vA, vH, vV, vD;
    {
        const float s_ab = gt0 + gt1, d_ab = gt0 - gt1;
        const float s_cd = gb0 + gb1, d_cd = gb0 - gb1;
        vA.x = (s_ab + s_cd) * 0.5f;  vH.x = (s_ab - s_cd) * 0.5f;
        vV.x = (d_ab + d_cd) * 0.5f;  vD.x = (d_ab - d_cd) * 0.5f;
    }
    {
        const float s_ab = gt2 + gt3, d_ab = gt2 - gt3;
        const float s_cd = gb2 + gb3, d_cd = gb2 - gb3;
        vA.y = (s_ab + s_cd) * 0.5f;  vH.y = (s_ab - s_cd) * 0.5f;
        vV.y = (d_ab + d_cd) * 0.5f;  vD.y = (d_ab - d_cd) * 0.5f;
    }
    {
        const float s_ab = gt4 + gt5, d_ab = gt4 - gt5;
        const float s_cd = gb4 + gb5, d_cd = gb4 - gb5;
        vA.z = (s_ab + s_cd) * 0.5f;  vH.z = (s_ab - s_cd) * 0.5f;
        vV.z = (d_ab + d_cd) * 0.5f;  vD.z = (d_ab - d_cd) * 0.5f;
    }
    {
        const float s_ab = gt6 + gt7, d_ab = gt6 - gt7;
        const float s_cd = gb6 + gb7, d_cd = gb6 - gb7;
        vA.w = (s_ab + s_cd) * 0.5f;  vH.w = (s_ab - s_cd) * 0.5f;
        vV.w = (d_ab + d_cd) * 0.5f;  vD.w = (d_ab - d_cd) * 0.5f;
    }

    // output: (b, k, i, j0..j0+3), plane stride OH_*OW_ ; 4 x 16B nt stores
    const size_t PL = (size_t)OH_ * OW_;
    float* op = out + ((size_t)b * 4) * PL + (size_t)i * OW_ + j0;
    __builtin_nontemporal_store(vA, reinterpret_cast<f4*>(op + 0 * PL));
    __builtin_nontemporal_store(vH, reinterpret_cast<f4*>(op + 1 * PL));
    __builtin_nontemporal_store(vV, reinterpret_cast<f4*>(op + 2 * PL));
    __builtin_nontemporal_store(vD, reinterpret_cast<f4*>(op + 3 * PL));
}

extern "C" void kernel_launch(void* const* d_in, const int* in_sizes, int n_in,
                              void* d_out, int out_size, void* d_ws, size_t ws_size,
                              hipStream_t stream) {
    const float* x = (const float*)d_in[0];
    float* out = (float*)d_out;

    const int total_threads = B_ * OH_ * (OW_ / 4);  // 1,048,576
    const int block = 256;
    const int grid = total_threads / block;          // 4096
    haar_gray_kernel<<<grid, block, 0, stream>>>(x, out);
}

// Round 14
// 287.541 us; speedup vs baseline: 1.0215x; 1.0215x over previous
//
#include <hip/hip_runtime.h>

// x: (16, 3, 1024, 1024) f32  ->  out: (16, 4, 512, 512) f32
// gray = 0.114*x[:,0] + 0.587*x[:,1] + 0.299*x[:,2]
// 2x2 Haar butterfly per 2x2 block; outputs 4 planes (cA,cH,cV,cD).
//
// Memory-bound: ideal traffic = 192 MiB in + 64 MiB out ~= 268 MB -> ~43 us
// at 6.3 TB/s. R13 lesson: 8-consecutive-cols/thread made each float4 load
// instruction HALF-DENSE across lanes (32B stride) -> 2x VMEM transactions.
// Fix: two lane-dense column groups 512 cols apart; every load instruction
// is now lane-contiguous (lane i -> base+16i). Stores: float2, lane-dense.

#define B_  16
#define H_  1024
#define W_  1024
#define OH_ 512
#define OW_ 512

__global__ __launch_bounds__(256) void haar_gray_kernel(
    const float* __restrict__ x, float* __restrict__ out)
{
    // one thread = 4 output pixels: 2 at cols [2t,2t+1], 2 at cols [256+2t,...]
    // total threads = 16 * 512 * 128 = 1,048,576
    const int tid = blockIdx.x * blockDim.x + threadIdx.x;

    const int b   = tid >> 16;              // batch
    const int rem = tid & 0xFFFF;
    const int i   = rem >> 7;               // output row (0..511)
    const int t   = rem & 127;              // lane-dense col-group index
    const int h0  = i << 1;                 // input row pair

    const float* bp = x + (size_t)b * 3 * H_ * W_;
    const size_t rowT = (size_t)h0 * W_;        // top input row offset
    const size_t rowB = rowT + W_;              // bottom input row offset
    const size_t CH = (size_t)H_ * W_;          // channel stride

    const float wb = 0.114f, wg = 0.587f, wr = 0.299f;

    // ---- left quad: input cols [4t, 4t+4) — all loads lane-dense ----
    const int wL = t << 2;
    const float4 L0t = *reinterpret_cast<const float4*>(bp + 0 * CH + rowT + wL);
    const float4 L0b = *reinterpret_cast<const float4*>(bp + 0 * CH + rowB + wL);
    const float4 L1t = *reinterpret_cast<const float4*>(bp + 1 * CH + rowT + wL);
    const float4 L1b = *reinterpret_cast<const float4*>(bp + 1 * CH + rowB + wL);
    const float4 L2t = *reinterpret_cast<const float4*>(bp + 2 * CH + rowT + wL);
    const float4 L2b = *reinterpret_cast<const float4*>(bp + 2 * CH + rowB + wL);

    // ---- right quad: input cols [512+4t, 512+4t+4) ----
    const int wR = wL + 512;
    const float4 R0t = *reinterpret_cast<const float4*>(bp + 0 * CH + rowT + wR);
    const float4 R0b = *reinterpret_cast<const float4*>(bp + 0 * CH + rowB + wR);
    const float4 R1t = *reinterpret_cast<const float4*>(bp + 1 * CH + rowT + wR);
    const float4 R1b = *reinterpret_cast<const float4*>(bp + 1 * CH + rowB + wR);
    const float4 R2t = *reinterpret_cast<const float4*>(bp + 2 * CH + rowT + wR);
    const float4 R2b = *reinterpret_cast<const float4*>(bp + 2 * CH + rowB + wR);

    // gray: left quad (4 top, 4 bottom)
    const float lt0 = fmaf(wb, L0t.x, fmaf(wg, L1t.x, wr * L2t.x));
    const float lt1 = fmaf(wb, L0t.y, fmaf(wg, L1t.y, wr * L2t.y));
    const float lt2 = fmaf(wb, L0t.z, fmaf(wg, L1t.z, wr * L2t.z));
    const float lt3 = fmaf(wb, L0t.w, fmaf(wg, L1t.w, wr * L2t.w));
    const float lb0 = fmaf(wb, L0b.x, fmaf(wg, L1b.x, wr * L2b.x));
    const float lb1 = fmaf(wb, L0b.y, fmaf(wg, L1b.y, wr * L2b.y));
    const float lb2 = fmaf(wb, L0b.z, fmaf(wg, L1b.z, wr * L2b.z));
    const float lb3 = fmaf(wb, L0b.w, fmaf(wg, L1b.w, wr * L2b.w));

    // gray: right quad
    const float rt0 = fmaf(wb, R0t.x, fmaf(wg, R1t.x, wr * R2t.x));
    const float rt1 = fmaf(wb, R0t.y, fmaf(wg, R1t.y, wr * R2t.y));
    const float rt2 = fmaf(wb, R0t.z, fmaf(wg, R1t.z, wr * R2t.z));
    const float rt3 = fmaf(wb, R0t.w, fmaf(wg, R1t.w, wr * R2t.w));
    const float rb0 = fmaf(wb, R0b.x, fmaf(wg, R1b.x, wr * R2b.x));
    const float rb1 = fmaf(wb, R0b.y, fmaf(wg, R1b.y, wr * R2b.y));
    const float rb2 = fmaf(wb, R0b.z, fmaf(wg, R1b.z, wr * R2b.z));
    const float rb3 = fmaf(wb, R0b.w, fmaf(wg, R1b.w, wr * R2b.w));

    // Haar butterfly: 2 blocks per quad -> float2 per plane per quad
    float2 LA, LH, LV, LD, RA, RH, RV, RD;
    {
        const float s_ab = lt0 + lt1, d_ab = lt0 - lt1;
        const float s_cd = lb0 + lb1, d_cd = lb0 - lb1;
        LA.x = (s_ab + s_cd) * 0.5f;  LH.x = (s_ab - s_cd) * 0.5f;
        LV.x = (d_ab + d_cd) * 0.5f;  LD.x = (d_ab - d_cd) * 0.5f;
    }
    {
        const float s_ab = lt2 + lt3, d_ab = lt2 - lt3;
        const float s_cd = lb2 + lb3, d_cd = lb2 - lb3;
        LA.y = (s_ab + s_cd) * 0.5f;  LH.y = (s_ab - s_cd) * 0.5f;
        LV.y = (d_ab + d_cd) * 0.5f;  LD.y = (d_ab - d_cd) * 0.5f;
    }
    {
        const float s_ab = rt0 + rt1, d_ab = rt0 - rt1;
        const float s_cd = rb0 + rb1, d_cd = rb0 - rb1;
        RA.x = (s_ab + s_cd) * 0.5f;  RH.x = (s_ab - s_cd) * 0.5f;
        RV.x = (d_ab + d_cd) * 0.5f;  RD.x = (d_ab - d_cd) * 0.5f;
    }
    {
        const float s_ab = rt2 + rt3, d_ab = rt2 - rt3;
        const float s_cd = rb2 + rb3, d_cd = rb2 - rb3;
        RA.y = (s_ab + s_cd) * 0.5f;  RH.y = (s_ab - s_cd) * 0.5f;
        RV.y = (d_ab + d_cd) * 0.5f;  RD.y = (d_ab - d_cd) * 0.5f;
    }

    // stores: 8 x float2, lane-dense (8B/lane). Left at col 2t, right at 256+2t.
    const size_t PL = (size_t)OH_ * OW_;
    float* opL = out + ((size_t)b * 4) * PL + (size_t)i * OW_ + (t << 1);
    float* opR = opL + 256;
    *reinterpret_cast<float2*>(opL + 0 * PL) = LA;
    *reinterpret_cast<float2*>(opR + 0 * PL) = RA;
    *reinterpret_cast<float2*>(opL + 1 * PL) = LH;
    *reinterpret_cast<float2*>(opR + 1 * PL) = RH;
    *reinterpret_cast<float2*>(opL + 2 * PL) = LV;
    *reinterpret_cast<float2*>(opR + 2 * PL) = RV;
    *reinterpret_cast<float2*>(opL + 3 * PL) = LD;
    *reinterpret_cast<float2*>(opR + 3 * PL) = RD;
}

extern "C" void kernel_launch(void* const* d_in, const int* in_sizes, int n_in,
                              void* d_out, int out_size, void* d_ws, size_t ws_size,
                              hipStream_t stream) {
    const float* x = (const float*)d_in[0];
    float* out = (float*)d_out;

    const int total_threads = B_ * OH_ * 128;  // 1,048,576
    const int block = 256;
    const int grid = total_threads / block;    // 4096
    haar_gray_kernel<<<grid, block, 0, stream>>>(x, out);
}